// Round 1
// baseline (481.314 us; speedup 1.0000x reference)
//
#include <hip/hip_runtime.h>
#include <hip/hip_bf16.h>

#define N_NODES 100000
#define N_EDGES 1600000
#define DIM 128

// ---------------- CSR build ----------------

__global__ void k_zero_cnt(int* __restrict__ cnt) {
    int i = blockIdx.x * blockDim.x + threadIdx.x;
    if (i < N_NODES) cnt[i] = 0;
}

__global__ void k_count(const int* __restrict__ dst, int* __restrict__ cnt) {
    int e = blockIdx.x * blockDim.x + threadIdx.x;
    if (e < N_EDGES) atomicAdd(&cnt[dst[e]], 1);
}

__global__ void k_dinv(const int* __restrict__ cnt, float* __restrict__ dinv) {
    int i = blockIdx.x * blockDim.x + threadIdx.x;
    if (i < N_NODES) dinv[i] = rsqrtf((float)(cnt[i] + 1));  // +1 self loop
}

// 3-phase exclusive scan of cnt[N] -> rp[N] (and nxt copy for fill cursors)
__global__ void k_scan_reduce(const int* __restrict__ cnt, int* __restrict__ bsum) {
    __shared__ int sm[1024];
    int t = threadIdx.x;
    int i = blockIdx.x * 1024 + t;
    sm[t] = (i < N_NODES) ? cnt[i] : 0;
    __syncthreads();
    for (int s = 512; s > 0; s >>= 1) {
        if (t < s) sm[t] += sm[t + s];
        __syncthreads();
    }
    if (t == 0) bsum[blockIdx.x] = sm[0];
}

__global__ void k_scan_bsum(int* __restrict__ bsum, int nb) {
    __shared__ int sm[128];
    int t = threadIdx.x;
    int v0 = (t < nb) ? bsum[t] : 0;
    sm[t] = v0;
    __syncthreads();
    for (int s = 1; s < 128; s <<= 1) {
        int v = (t >= s) ? sm[t - s] : 0;
        __syncthreads();
        sm[t] += v;
        __syncthreads();
    }
    if (t < nb) bsum[t] = sm[t] - v0;  // exclusive
}

__global__ void k_scan_apply(const int* __restrict__ cnt, const int* __restrict__ bsum,
                             int* __restrict__ rp, int* __restrict__ nxt) {
    __shared__ int sm[1024];
    int t = threadIdx.x;
    int i = blockIdx.x * 1024 + t;
    int v0 = (i < N_NODES) ? cnt[i] : 0;
    sm[t] = v0;
    __syncthreads();
    for (int s = 1; s < 1024; s <<= 1) {
        int v = (t >= s) ? sm[t - s] : 0;
        __syncthreads();
        sm[t] += v;
        __syncthreads();
    }
    if (i < N_NODES) {
        int excl = sm[t] - v0 + bsum[blockIdx.x];
        rp[i] = excl;
        nxt[i] = excl;
    }
}

__global__ void k_fill(const int* __restrict__ src, const int* __restrict__ dst,
                       int* __restrict__ nxt, int* __restrict__ csr_src) {
    int e = blockIdx.x * blockDim.x + threadIdx.x;
    if (e < N_EDGES) {
        int d = dst[e];
        int p = atomicAdd(&nxt[d], 1);
        csr_src[p] = src[e];
    }
}

// ---------------- GEMM: h1 = x @ W1 (fp32, W1 + x-tile in LDS) ----------------

#define GEMM_TILES (N_NODES / 32)  // 3125, exact

__global__ __launch_bounds__(256) void k_gemm(const float* __restrict__ x,
                                              const float* __restrict__ W1,
                                              float* __restrict__ h1) {
    __shared__ float Wlds[DIM * DIM];   // 64 KB
    __shared__ float xlds[32 * DIM];    // 16 KB
    int tid = threadIdx.x;
    for (int idx = tid; idx < DIM * DIM / 4; idx += 256)
        ((float4*)Wlds)[idx] = ((const float4*)W1)[idx];

    int col4 = (tid & 31) * 4;   // output columns [col4, col4+4)
    int rowgrp = tid >> 5;       // 0..7, each handles 4 rows

    for (int tile = blockIdx.x; tile < GEMM_TILES; tile += gridDim.x) {
        int rows_base = tile * 32;
        __syncthreads();  // xlds safe to overwrite; also orders W load before 1st use
        for (int idx = tid; idx < 32 * DIM / 4; idx += 256)
            ((float4*)xlds)[idx] = ((const float4*)(x + (size_t)rows_base * DIM))[idx];
        __syncthreads();

        float4 acc[4];
#pragma unroll
        for (int r = 0; r < 4; ++r) acc[r] = make_float4(0.f, 0.f, 0.f, 0.f);

        for (int k = 0; k < DIM; k += 4) {
            float4 xv[4];
#pragma unroll
            for (int r = 0; r < 4; ++r)
                xv[r] = *(const float4*)&xlds[(rowgrp * 4 + r) * DIM + k];
#pragma unroll
            for (int kk = 0; kk < 4; ++kk) {
                float4 wv = *(const float4*)&Wlds[(k + kk) * DIM + col4];
#pragma unroll
                for (int r = 0; r < 4; ++r) {
                    float xs = (kk == 0) ? xv[r].x : (kk == 1) ? xv[r].y : (kk == 2) ? xv[r].z : xv[r].w;
                    acc[r].x = fmaf(xs, wv.x, acc[r].x);
                    acc[r].y = fmaf(xs, wv.y, acc[r].y);
                    acc[r].z = fmaf(xs, wv.z, acc[r].z);
                    acc[r].w = fmaf(xs, wv.w, acc[r].w);
                }
            }
        }
#pragma unroll
        for (int r = 0; r < 4; ++r) {
            int row = rows_base + rowgrp * 4 + r;
            *(float4*)&h1[(size_t)row * DIM + col4] = acc[r];
        }
    }
}

// ---------------- Fused: agg1 + b1 + ReLU + (r @ W2) -> z[N] ----------------
// one wave per node; lane owns 2 columns

__global__ __launch_bounds__(256) void k_agg1(const float* __restrict__ h1,
                                              const float* __restrict__ dinv,
                                              const int* __restrict__ rp,
                                              const int* __restrict__ cnt,
                                              const int* __restrict__ csr_src,
                                              const float* __restrict__ b1,
                                              const float* __restrict__ W2,
                                              float* __restrict__ z) {
    int wave = threadIdx.x >> 6;
    int lane = threadIdx.x & 63;
    int i = blockIdx.x * 4 + wave;
    if (i >= N_NODES) return;

    float di = dinv[i];
    int beg = rp[i];
    int num = cnt[i];
    int c0 = lane * 2;

    float a0 = 0.f, a1 = 0.f;
    for (int j = beg; j < beg + num; ++j) {
        int s = csr_src[j];
        float ns = dinv[s] * di;
        float2 hv = *(const float2*)&h1[(size_t)s * DIM + c0];
        a0 = fmaf(hv.x, ns, a0);
        a1 = fmaf(hv.y, ns, a1);
    }
    float2 hs = *(const float2*)&h1[(size_t)i * DIM + c0];
    float sii = di * di;
    float r0 = fmaxf(fmaf(hs.x, sii, a0) + b1[c0], 0.f);
    float r1 = fmaxf(fmaf(hs.y, sii, a1) + b1[c0 + 1], 0.f);
    float p = r0 * W2[c0] + r1 * W2[c0 + 1];
#pragma unroll
    for (int off = 32; off > 0; off >>= 1) p += __shfl_down(p, off, 64);
    if (lane == 0) z[i] = p;  // b2 added in agg2
}

// ---------------- agg2: out[i] = di*sum(z[s]*dinv[s]) + z[i]*di^2 + b2 ----------------

__global__ void k_agg2(const float* __restrict__ zin, const float* __restrict__ dinv,
                       const int* __restrict__ rp, const int* __restrict__ cnt,
                       const int* __restrict__ csr_src, const float* __restrict__ b2,
                       float* __restrict__ out) {
    int i = blockIdx.x * blockDim.x + threadIdx.x;
    if (i >= N_NODES) return;
    float di = dinv[i];
    int beg = rp[i], num = cnt[i];
    float acc = 0.f;
    for (int j = beg; j < beg + num; ++j) {
        int s = csr_src[j];
        acc = fmaf(zin[s], dinv[s], acc);
    }
    out[i] = di * acc + zin[i] * di * di + b2[0];
}

// ---------------- launch ----------------

extern "C" void kernel_launch(void* const* d_in, const int* in_sizes, int n_in,
                              void* d_out, int out_size, void* d_ws, size_t ws_size,
                              hipStream_t stream) {
    const float* x  = (const float*)d_in[0];
    const int*   ei = (const int*)d_in[1];     // [2, E] int32
    const float* W1 = (const float*)d_in[2];
    const float* b1 = (const float*)d_in[3];
    const float* W2 = (const float*)d_in[4];
    const float* b2 = (const float*)d_in[5];
    float* out = (float*)d_out;

    const int* src = ei;
    const int* dst = ei + N_EDGES;

    char* ws = (char*)d_ws;
    size_t o = 0;
    auto take = [&](size_t bytes) { char* p = ws + o; o += (bytes + 255) & ~(size_t)255; return p; };
    int*   cnt  = (int*)take(sizeof(int) * N_NODES);
    int*   rp   = (int*)take(sizeof(int) * N_NODES);
    int*   nxt  = (int*)take(sizeof(int) * N_NODES);
    int*   bsum = (int*)take(sizeof(int) * 128);
    float* dinv = (float*)take(sizeof(float) * N_NODES);
    float* z    = (float*)take(sizeof(float) * N_NODES);
    int*   csr  = (int*)take(sizeof(int) * N_EDGES);
    float* h1   = (float*)take(sizeof(float) * (size_t)N_NODES * DIM);

    const int NB_N = (N_NODES + 255) / 256;
    const int NB_E = (N_EDGES + 255) / 256;
    const int NB_SCAN = (N_NODES + 1023) / 1024;  // 98

    k_zero_cnt<<<NB_N, 256, 0, stream>>>(cnt);
    k_count<<<NB_E, 256, 0, stream>>>(dst, cnt);
    k_dinv<<<NB_N, 256, 0, stream>>>(cnt, dinv);
    k_scan_reduce<<<NB_SCAN, 1024, 0, stream>>>(cnt, bsum);
    k_scan_bsum<<<1, 128, 0, stream>>>(bsum, NB_SCAN);
    k_scan_apply<<<NB_SCAN, 1024, 0, stream>>>(cnt, bsum, rp, nxt);
    k_fill<<<NB_E, 256, 0, stream>>>(src, dst, nxt, csr);
    k_gemm<<<640, 256, 0, stream>>>(x, W1, h1);
    k_agg1<<<N_NODES / 4, 256, 0, stream>>>(h1, dinv, rp, cnt, csr, b1, W2, z);
    k_agg2<<<NB_N, 256, 0, stream>>>(z, dinv, rp, cnt, csr, b2, out);
}

// Round 2
// 284.406 us; speedup vs baseline: 1.6923x; 1.6923x over previous
//
#include <hip/hip_runtime.h>

#define N_NODES 100000
#define N_EDGES 1600000
#define DIM 128

typedef short s16x8 __attribute__((ext_vector_type(8)));
typedef float f32x4 __attribute__((ext_vector_type(4)));

__device__ __forceinline__ unsigned short f2bf(float f) {
    unsigned u = __float_as_uint(f);
    u += 0x7fffu + ((u >> 16) & 1u);   // RNE (NaN not expected in data)
    return (unsigned short)(u >> 16);
}
__device__ __forceinline__ float bflo(unsigned u) { return __uint_as_float(u << 16); }
__device__ __forceinline__ float bfhi(unsigned u) { return __uint_as_float(u & 0xffff0000u); }

// ---------------- CSR build ----------------

__global__ void k_zero_cnt(int* __restrict__ cnt) {
    int i = blockIdx.x * blockDim.x + threadIdx.x;
    if (i < N_NODES) cnt[i] = 0;
}

__global__ void k_count(const int* __restrict__ dst, int* __restrict__ cnt) {
    int e = blockIdx.x * blockDim.x + threadIdx.x;
    if (e < N_EDGES) atomicAdd(&cnt[dst[e]], 1);
}

__global__ void k_dinv(const int* __restrict__ cnt, float* __restrict__ dinv) {
    int i = blockIdx.x * blockDim.x + threadIdx.x;
    if (i < N_NODES) dinv[i] = rsqrtf((float)(cnt[i] + 1));  // +1 self loop
}

__global__ void k_scan_reduce(const int* __restrict__ cnt, int* __restrict__ bsum) {
    __shared__ int sm[1024];
    int t = threadIdx.x;
    int i = blockIdx.x * 1024 + t;
    sm[t] = (i < N_NODES) ? cnt[i] : 0;
    __syncthreads();
    for (int s = 512; s > 0; s >>= 1) {
        if (t < s) sm[t] += sm[t + s];
        __syncthreads();
    }
    if (t == 0) bsum[blockIdx.x] = sm[0];
}

__global__ void k_scan_bsum(int* __restrict__ bsum, int nb) {
    __shared__ int sm[128];
    int t = threadIdx.x;
    int v0 = (t < nb) ? bsum[t] : 0;
    sm[t] = v0;
    __syncthreads();
    for (int s = 1; s < 128; s <<= 1) {
        int v = (t >= s) ? sm[t - s] : 0;
        __syncthreads();
        sm[t] += v;
        __syncthreads();
    }
    if (t < nb) bsum[t] = sm[t] - v0;  // exclusive
}

__global__ void k_scan_apply(const int* __restrict__ cnt, const int* __restrict__ bsum,
                             int* __restrict__ rp, int* __restrict__ nxt) {
    __shared__ int sm[1024];
    int t = threadIdx.x;
    int i = blockIdx.x * 1024 + t;
    int v0 = (i < N_NODES) ? cnt[i] : 0;
    sm[t] = v0;
    __syncthreads();
    for (int s = 1; s < 1024; s <<= 1) {
        int v = (t >= s) ? sm[t - s] : 0;
        __syncthreads();
        sm[t] += v;
        __syncthreads();
    }
    if (i < N_NODES) {
        int excl = sm[t] - v0 + bsum[blockIdx.x];
        rp[i] = excl;
        nxt[i] = excl;
    }
}

// fill CSR with packed (src, norm-weight) pairs: w = dinv[src]*dinv[dst]
__global__ void k_fill(const int* __restrict__ src, const int* __restrict__ dst,
                       const float* __restrict__ dinv,
                       int* __restrict__ nxt, int2* __restrict__ csrw) {
    int e = blockIdx.x * blockDim.x + threadIdx.x;
    if (e < N_EDGES) {
        int s = src[e], d = dst[e];
        int p = atomicAdd(&nxt[d], 1);
        float w = dinv[s] * dinv[d];
        csrw[p] = make_int2(s, __float_as_int(w));
    }
}

// ---------------- GEMM: h1(bf16) = x @ W1 via bf16 MFMA ----------------
// block = 4 waves, 64 rows/tile; wave = 16 rows x 128 cols.
// Wt: W1 transposed to [col][k] bf16 in LDS, XOR-swizzled (T2).
// C: per-wave LDS bounce (swizzled) -> coalesced dwordx4 bf16 stores.

#define GTILES 1563   // ceil(100000/64); 16 | N so per-wave guard suffices
#define GGRID  782

__global__ __launch_bounds__(256) void k_gemm(const float* __restrict__ x,
                                              const float* __restrict__ W1,
                                              unsigned short* __restrict__ h1) {
    __shared__ uint4 WtB[2048];     // 32 KB: Wt[c][k] bf16, swizzled
    __shared__ uint4 CstB[4][256];  // 4 KB per wave C-staging
    unsigned short* Wt = (unsigned short*)WtB;
    int tid = threadIdx.x;
    for (int idx = tid; idx < DIM * DIM; idx += 256) {
        int k = idx >> 7, c = idx & 127;
        Wt[c * 128 + (k ^ ((c & 7) << 3))] = f2bf(W1[idx]);
    }
    __syncthreads();

    int wv = tid >> 6, lane = tid & 63;
    int g = lane >> 4, tl = lane & 15;
    unsigned short* cst = (unsigned short*)&CstB[wv][0];

    for (int tile = blockIdx.x; tile < GTILES; tile += GGRID) {
        int rb = tile * 64 + wv * 16;
        if (rb >= N_NODES) continue;

        // A fragments from global (row = rb+tl, k-octet = g*8 within each 32-chunk)
        s16x8 afrag[4];
        const float* xrow = x + (size_t)(rb + tl) * DIM + g * 8;
#pragma unroll
        for (int kc = 0; kc < 4; ++kc) {
            float4 p0 = *(const float4*)(xrow + kc * 32);
            float4 p1 = *(const float4*)(xrow + kc * 32 + 4);
            s16x8 a;
            a[0] = (short)f2bf(p0.x); a[1] = (short)f2bf(p0.y);
            a[2] = (short)f2bf(p0.z); a[3] = (short)f2bf(p0.w);
            a[4] = (short)f2bf(p1.x); a[5] = (short)f2bf(p1.y);
            a[6] = (short)f2bf(p1.z); a[7] = (short)f2bf(p1.w);
            afrag[kc] = a;
        }

        f32x4 acc[8];
#pragma unroll
        for (int ct = 0; ct < 8; ++ct) acc[ct] = (f32x4)0.0f;
#pragma unroll
        for (int kc = 0; kc < 4; ++kc) {
#pragma unroll
            for (int ct = 0; ct < 8; ++ct) {
                int crow = ct * 16 + tl;
                int boff = crow * 256 + ((kc * 64 + g * 16) ^ ((crow & 7) << 4));
                s16x8 b = *(const s16x8*)((const char*)Wt + boff);
                acc[ct] = __builtin_amdgcn_mfma_f32_16x16x32_bf16(afrag[kc], b, acc[ct], 0, 0, 0);
            }
        }

        // D frag: row=(lane>>4)*4+r, col=ct*16+(lane&15)  [m89-verified layout]
        // pack col pairs via shfl_xor(1), even lanes write b32, swizzle col ^= row<<3
#pragma unroll
        for (int ct = 0; ct < 8; ++ct) {
#pragma unroll
            for (int r = 0; r < 4; ++r) {
                float own = acc[ct][r];
                float oth = __shfl_xor(own, 1, 64);
                if ((lane & 1) == 0) {
                    unsigned pk = (unsigned)f2bf(own) | ((unsigned)f2bf(oth) << 16);
                    int row = g * 4 + r;
                    int col = ct * 16 + tl;  // even
                    *(unsigned*)&cst[row * 128 + (col ^ (row << 3))] = pk;
                }
            }
        }
        asm volatile("s_waitcnt lgkmcnt(0)" ::: "memory");  // per-wave LDS drain

        // readback (inverse swizzle: phys chunk = j ^ row) + coalesced store
        unsigned short* dstp = h1 + (size_t)rb * DIM;
#pragma unroll
        for (int c = 0; c < 4; ++c) {
            int row = c * 4 + g;
            uint4 v = *(const uint4*)&cst[row * 128 + ((tl ^ row) * 8)];
            *(uint4*)(dstp + c * 512 + lane * 8) = v;
        }
    }
}

// ---------------- agg1 + b1 + ReLU + (r @ W2) -> z[N] ----------------
// 16-lane group per node (4 nodes/wave), lane owns 8 cols (16 B gather/lane).

__global__ __launch_bounds__(256) void k_agg1(const unsigned short* __restrict__ h1,
                                              const float* __restrict__ dinv,
                                              const int* __restrict__ rp,
                                              const int* __restrict__ cnt,
                                              const int2* __restrict__ csrw,
                                              const float* __restrict__ b1,
                                              const float* __restrict__ W2,
                                              float* __restrict__ z) {
    int lane = threadIdx.x & 63;
    int wv = threadIdx.x >> 6;
    int g = lane >> 4, tl = lane & 15;
    int i = blockIdx.x * 16 + wv * 4 + g;  // grid = 6250 exact
    int c0 = tl * 8;
    float di = dinv[i];
    int beg = rp[i], end = beg + cnt[i];
    float a0 = 0.f, a1 = 0.f, a2 = 0.f, a3 = 0.f, a4 = 0.f, a5 = 0.f, a6 = 0.f, a7 = 0.f;
    const unsigned short* hbase = h1 + c0;

    int j = beg;
    for (; j + 2 <= end; j += 2) {
        int2 e0 = csrw[j];
        int2 e1 = csrw[j + 1];
        uint4 v0 = *(const uint4*)(hbase + (size_t)e0.x * DIM);
        uint4 v1 = *(const uint4*)(hbase + (size_t)e1.x * DIM);
        float w0 = __int_as_float(e0.y), w1 = __int_as_float(e1.y);
        a0 = fmaf(bflo(v0.x), w0, a0); a1 = fmaf(bfhi(v0.x), w0, a1);
        a2 = fmaf(bflo(v0.y), w0, a2); a3 = fmaf(bfhi(v0.y), w0, a3);
        a4 = fmaf(bflo(v0.z), w0, a4); a5 = fmaf(bfhi(v0.z), w0, a5);
        a6 = fmaf(bflo(v0.w), w0, a6); a7 = fmaf(bfhi(v0.w), w0, a7);
        a0 = fmaf(bflo(v1.x), w1, a0); a1 = fmaf(bfhi(v1.x), w1, a1);
        a2 = fmaf(bflo(v1.y), w1, a2); a3 = fmaf(bfhi(v1.y), w1, a3);
        a4 = fmaf(bflo(v1.z), w1, a4); a5 = fmaf(bfhi(v1.z), w1, a5);
        a6 = fmaf(bflo(v1.w), w1, a6); a7 = fmaf(bfhi(v1.w), w1, a7);
    }
    if (j < end) {
        int2 e0 = csrw[j];
        uint4 v0 = *(const uint4*)(hbase + (size_t)e0.x * DIM);
        float w0 = __int_as_float(e0.y);
        a0 = fmaf(bflo(v0.x), w0, a0); a1 = fmaf(bfhi(v0.x), w0, a1);
        a2 = fmaf(bflo(v0.y), w0, a2); a3 = fmaf(bfhi(v0.y), w0, a3);
        a4 = fmaf(bflo(v0.z), w0, a4); a5 = fmaf(bfhi(v0.z), w0, a5);
        a6 = fmaf(bflo(v0.w), w0, a6); a7 = fmaf(bfhi(v0.w), w0, a7);
    }

    uint4 vs = *(const uint4*)(hbase + (size_t)i * DIM);
    float sii = di * di;
    float4 bA = *(const float4*)(b1 + c0);
    float4 bB = *(const float4*)(b1 + c0 + 4);
    float4 wA = *(const float4*)(W2 + c0);
    float4 wB = *(const float4*)(W2 + c0 + 4);
    float p = 0.f;
    p += fmaxf(fmaf(bflo(vs.x), sii, a0) + bA.x, 0.f) * wA.x;
    p += fmaxf(fmaf(bfhi(vs.x), sii, a1) + bA.y, 0.f) * wA.y;
    p += fmaxf(fmaf(bflo(vs.y), sii, a2) + bA.z, 0.f) * wA.z;
    p += fmaxf(fmaf(bfhi(vs.y), sii, a3) + bA.w, 0.f) * wA.w;
    p += fmaxf(fmaf(bflo(vs.z), sii, a4) + bB.x, 0.f) * wB.x;
    p += fmaxf(fmaf(bfhi(vs.z), sii, a5) + bB.y, 0.f) * wB.y;
    p += fmaxf(fmaf(bflo(vs.w), sii, a6) + bB.z, 0.f) * wB.z;
    p += fmaxf(fmaf(bfhi(vs.w), sii, a7) + bB.w, 0.f) * wB.w;
#pragma unroll
    for (int off = 8; off >= 1; off >>= 1) p += __shfl_xor(p, off, 64);
    if (tl == 0) z[i] = p;  // b2 added in agg2
}

// ---------------- agg2: out[i] = sum(w*z[s]) + z[i]*di^2 + b2 ----------------

__global__ __launch_bounds__(256) void k_agg2(const float* __restrict__ zin,
                                              const float* __restrict__ dinv,
                                              const int* __restrict__ rp,
                                              const int* __restrict__ cnt,
                                              const int2* __restrict__ csrw,
                                              const float* __restrict__ b2,
                                              float* __restrict__ out) {
    int i = blockIdx.x * blockDim.x + threadIdx.x;
    if (i >= N_NODES) return;
    float di = dinv[i];
    int beg = rp[i], end = beg + cnt[i];
    float acc = 0.f;
    int j = beg;
    for (; j + 4 <= end; j += 4) {
        int2 e0 = csrw[j], e1 = csrw[j + 1], e2 = csrw[j + 2], e3 = csrw[j + 3];
        float z0 = zin[e0.x], z1 = zin[e1.x], z2 = zin[e2.x], z3 = zin[e3.x];
        acc = fmaf(z0, __int_as_float(e0.y), acc);
        acc = fmaf(z1, __int_as_float(e1.y), acc);
        acc = fmaf(z2, __int_as_float(e2.y), acc);
        acc = fmaf(z3, __int_as_float(e3.y), acc);
    }
    for (; j < end; ++j) {
        int2 e = csrw[j];
        acc = fmaf(zin[e.x], __int_as_float(e.y), acc);
    }
    out[i] = acc + zin[i] * di * di + b2[0];
}

// ---------------- launch ----------------

extern "C" void kernel_launch(void* const* d_in, const int* in_sizes, int n_in,
                              void* d_out, int out_size, void* d_ws, size_t ws_size,
                              hipStream_t stream) {
    const float* x  = (const float*)d_in[0];
    const int*   ei = (const int*)d_in[1];
    const float* W1 = (const float*)d_in[2];
    const float* b1 = (const float*)d_in[3];
    const float* W2 = (const float*)d_in[4];
    const float* b2 = (const float*)d_in[5];
    float* out = (float*)d_out;

    const int* src = ei;
    const int* dst = ei + N_EDGES;

    char* ws = (char*)d_ws;
    size_t o = 0;
    auto take = [&](size_t bytes) { char* p = ws + o; o += (bytes + 255) & ~(size_t)255; return p; };
    int*   cnt  = (int*)take(sizeof(int) * N_NODES);
    int*   rp   = (int*)take(sizeof(int) * N_NODES);
    int*   nxt  = (int*)take(sizeof(int) * N_NODES);
    int*   bsum = (int*)take(sizeof(int) * 128);
    float* dinv = (float*)take(sizeof(float) * N_NODES);
    float* z    = (float*)take(sizeof(float) * N_NODES);
    int2*  csrw = (int2*)take(sizeof(int2) * N_EDGES);
    unsigned short* h1 = (unsigned short*)take(sizeof(unsigned short) * (size_t)N_NODES * DIM);

    const int NB_N = (N_NODES + 255) / 256;
    const int NB_E = (N_EDGES + 255) / 256;
    const int NB_SCAN = (N_NODES + 1023) / 1024;  // 98

    k_zero_cnt<<<NB_N, 256, 0, stream>>>(cnt);
    k_count<<<NB_E, 256, 0, stream>>>(dst, cnt);
    k_dinv<<<NB_N, 256, 0, stream>>>(cnt, dinv);
    k_scan_reduce<<<NB_SCAN, 1024, 0, stream>>>(cnt, bsum);
    k_scan_bsum<<<1, 128, 0, stream>>>(bsum, NB_SCAN);
    k_scan_apply<<<NB_SCAN, 1024, 0, stream>>>(cnt, bsum, rp, nxt);
    k_fill<<<NB_E, 256, 0, stream>>>(src, dst, dinv, nxt, csrw);
    k_gemm<<<GGRID, 256, 0, stream>>>(x, W1, h1);
    k_agg1<<<N_NODES / 16, 256, 0, stream>>>(h1, dinv, rp, cnt, csrw, b1, W2, z);
    k_agg2<<<NB_N, 256, 0, stream>>>(z, dinv, rp, cnt, csrw, b2, out);
}